// Round 6
// baseline (326.595 us; speedup 1.0000x reference)
//
#include <hip/hip_runtime.h>

// StockLSTM R19: 2 independent blocks/CU at 256-reg budget (the spill-free way).
//  R18 proved: halving LDS front + wave count = ZERO change -> the step time is
//  the serial skeleton (barrier, ds latency, MFMA chain, trans chain) shared by
//  all barrier-locked waves. Fix needs a second barrier DOMAIN per CU.
//  R14/R15/R17 spilled at 64/128-reg budgets; R18 showed waves_per_eu(2,2)
//  gives 256 regs spill-free. So: 256-thread blocks (4 waves), MT=8, grid=512
//  -> 2 blocks/CU @ 2 waves/SIMD. Each wave owns 4 L1 + 4 L2 row-tiles
//  (28 MFMA/step, weights 112 VGPR, ~200 live < 256). Batch-8 fills 16 MFMA
//  cols by broadcast-read dup (lanes b8/b8+8 read same LDS addr -> cols 0-7
//  == cols 8-15, every lane holds valid output). Lane half sel owns 4 REAL
//  cells: sel0 -> the 4 L1 units (16w+4s+q), sel1 -> the 4 L2 units.
//  Per-CU VALU unchanged; per-thread math bit-identical to R13/R18.
//  MFMA/CU-step doubles to 224 (~45-55% util target) -- pipe had headroom.
//  SENTINELS: VGPR ~190-220 + WRITE_SIZE ~400 KB (no spill); flat 215 us
//  means blocks failed to overlap -> serial skeleton is the true floor.

#define TT   256
#define II   5
#define HH   64
#define OO   25
#define MT   8
#define NTHR 256
#define XP   520        // x chunk row stride (ushorts): 64*8 + 8 skew
#define HSZ  512        // h parity block: 64 k * 8 batch shorts
#define HF   65

typedef __attribute__((ext_vector_type(8))) short  short8;
typedef __attribute__((ext_vector_type(4))) float  floatx4;

#define MFMA(a, b, c) __builtin_amdgcn_mfma_f32_16x16x32_bf16(a, b, c, 0, 0, 0)

__device__ __forceinline__ float frcp(float x) { return __builtin_amdgcn_rcpf(x); }
__device__ __forceinline__ float fexp2(float x) { return __builtin_amdgcn_exp2f(x); }
__device__ __forceinline__ unsigned short bf16_rne(float f) {
    unsigned int u = __builtin_bit_cast(unsigned int, f);
    u += 0x7FFFu + ((u >> 16) & 1u);
    return (unsigned short)(u >> 16);
}
// gates arrive PRE-SCALED: g0,g1,g3 = -log2e*z ; g2 = +2log2e*z
__device__ __forceinline__ float cell_update(const floatx4& g, float& c) {
    const float gi = frcp(1.f + fexp2(g[0]));
    const float gf = frcp(1.f + fexp2(g[1]));
    const float gz = fmaf(-2.f, frcp(1.f + fexp2(g[2])), 1.f);
    const float go = frcp(1.f + fexp2(g[3]));
    c = fmaf(gf, c, gi * gz);
    const float tc = fmaf(-2.f, frcp(1.f + fexp2(c * 2.885390082f)), 1.f);
    return go * tc;
}

__global__ __attribute__((amdgpu_flat_work_group_size(256, 256),
                          amdgpu_waves_per_eu(2, 2)))
void lstm_mfma15(const float* __restrict__ x,
                 const float* __restrict__ Wih0, const float* __restrict__ Whh0,
                 const float* __restrict__ bih0, const float* __restrict__ bhh0,
                 const float* __restrict__ Wih1, const float* __restrict__ Whh1,
                 const float* __restrict__ bih1, const float* __restrict__ bhh1,
                 const float* __restrict__ Wfc,  const float* __restrict__ bfc,
                 float* __restrict__ out)
{
    __shared__ __align__(16) unsigned short xhi[MT * XP];     // 8.3 KB
    __shared__ __align__(16) unsigned short h1hi[2 * HSZ];    // 2 KB
    __shared__ __align__(16) unsigned short h2hi[2 * HSZ];    // 2 KB
    __shared__ __align__(16) float          h2f[MT * HF];     // 2.1 KB

    const int tid   = threadIdx.x;
    const int w     = tid >> 6;          // wave 0..3: owns tiles 4w..4w+3 (both layers)
    const int lane  = tid & 63;
    const int b8    = lane & 7;          // batch col (8 real; cols 8-15 = dup)
    const int q     = lane >> 4;         // C row-quad / unit offset within tile
    const bool isl2 = ((lane >> 3) & 1) != 0;   // sel: 0 -> own L1 cells, 1 -> own L2
    // h storage: [j>>3][b8][j&7] shorts. Lane's unit for tile s: j = 16w+4s+q.
    const int hw_base = w * 128 + b8 * 8 + q;   // + {0,4,64,68} for s=0..3
    const int ro8     = (q * 8 + b8) * 8;       // B-frag read: b8/b8+8 broadcast

    // ---------------- weights (bf16), nonlinearity scale folded in ----------------
    short8 A1h[4][2];   // [tile][k-chunk] Whh0
    short8 A2h[4][4];   // [tile][k-chunk] 0,1: Wih1 (h1); 2,3: Whh1 (h2)
    short8 Axwh[4];     // [tile] Wih0: k<II valid, rest exact zero
    {
        const int rr = lane & 15;
        const float sc = ((rr & 3) == 2) ? 2.885390082f : -1.442695041f;
        #pragma unroll
        for (int s = 0; s < 4; ++s) {
            const int g = (rr & 3) * 64 + 16 * w + 4 * s + (rr >> 2);
            #pragma unroll
            for (int c = 0; c < 2; ++c)
                #pragma unroll
                for (int jj = 0; jj < 8; ++jj)
                    A1h[s][c][jj] = (short)bf16_rne(sc * Whh0[g * HH + c * 32 + q * 8 + jj]);
            #pragma unroll
            for (int c = 0; c < 4; ++c)
                #pragma unroll
                for (int jj = 0; jj < 8; ++jj) {
                    const int k = c * 32 + q * 8 + jj;
                    float wv = (k < HH) ? Wih1[g * HH + k] : Whh1[g * HH + (k - HH)];
                    A2h[s][c][jj] = (short)bf16_rne(sc * wv);
                }
            #pragma unroll
            for (int jj = 0; jj < 8; ++jj) {
                const int k = q * 8 + jj;
                Axwh[s][jj] = (k < II) ? (short)bf16_rne(sc * Wih0[g * II + k]) : (short)0;
            }
        }
    }
    // bias as MFMA C-operand: per tile, lane's 4 gate rows of unit 16w+4s+q.
    floatx4 bias1v[4], bias2v[4];
    #pragma unroll
    for (int s = 0; s < 4; ++s) {
        const int jj = 16 * w + 4 * s + q;
        #pragma unroll
        for (int r = 0; r < 4; ++r) {
            const int g = r * 64 + jj;
            const float sc = (r == 2) ? 2.885390082f : -1.442695041f;
            bias1v[s][r] = sc * (bih0[g] + bhh0[g]);
            bias2v[s][r] = sc * (bih1[g] + bhh1[g]);
        }
    }

    // ---------------- zero LDS ----------------
    for (int i = tid; i < MT * XP / 2; i += NTHR)
        ((unsigned int*)xhi)[i] = 0u;
    for (int i = tid; i < HSZ; i += NTHR) {      // HSZ uints = 2*HSZ shorts
        ((unsigned int*)h1hi)[i] = 0u;
        ((unsigned int*)h2hi)[i] = 0u;
    }
    float cst0 = 0.f, cst1 = 0.f, cst2 = 0.f, cst3 = 0.f;  // lane's 4 cell states
    __syncthreads();

    const int blockBase = blockIdx.x * MT;

    auto refill_x = [&](int t0) {
        const int rb = tid >> 6, dt = tid & 63;   // rb 0..3 -> rows rb, rb+4
        #pragma unroll
        for (int rr2 = rb; rr2 < MT; rr2 += 4) {
            const float* src = x + ((size_t)(blockBase + rr2) * TT + t0 + dt) * II;
            unsigned short* ph = xhi + rr2 * XP + dt * 8;
            #pragma unroll
            for (int ii = 0; ii < II; ++ii)
                ph[ii] = bf16_rne(src[ii]);
        }
    };

    // per-lane h write pointers (parity baked in; +{0,4,64,68} per tile s):
    //  even intervals (WP=0,RP=1): sel0 writes h1[1], sel1 writes h2[0]
    //  odd  intervals (WP=1,RP=0): sel0 writes h1[0], sel1 writes h2[1]
    unsigned short* const hpE = (isl2 ? h2hi + 0 * HSZ : h1hi + 1 * HSZ) + hw_base;
    unsigned short* const hpO = (isl2 ? h2hi + 1 * HSZ : h1hi + 0 * HSZ) + hw_base;

    // ================= prologue: L1(0) =================
    refill_x(0);
    __syncthreads();
    {
        short8 Bxh = *(const short8*)(xhi + b8 * XP);       // dt = 0
        #pragma unroll
        for (int s = 0; s < 4; ++s) {
            floatx4 a1 = MFMA(Axwh[s], Bxh, bias1v[s]);
            if (!isl2) {
                float& cs = (s == 0) ? cst0 : (s == 1) ? cst1 : (s == 2) ? cst2 : cst3;
                const float h = cell_update(a1, cs);
                h1hi[0 * HSZ + hw_base + ((s & 2) << 5) + ((s & 1) << 2)] = bf16_rne(h);
            }
        }
    }
    __syncthreads();

    // x read pointer: STEP(i) reads dt=(i+1)&63; starts at dt=1.
    const unsigned short* xptr = xhi + b8 * XP + 8;

    // ================= merged main loop, unrolled by 2 =================
    // Per tile s: L2 4-MFMA chain, L1 3-MFMA chain, 4x cndmask select,
    // ONE real cell per lane, write via parity pointer + immediate.
#define STEP_BODY(WP, RP, HP)                                                 \
    {                                                                         \
        short8 H1h0 = *(const short8*)(h1hi + (WP) * HSZ + ro8);              \
        short8 H1h1 = *(const short8*)(h1hi + (WP) * HSZ + 256 + ro8);        \
        short8 H2h0 = *(const short8*)(h2hi + (RP) * HSZ + ro8);              \
        short8 H2h1 = *(const short8*)(h2hi + (RP) * HSZ + 256 + ro8);        \
        short8 Bxh  = *(const short8*)(xptr);                                 \
        xptr += 8;                                                            \
        _Pragma("unroll")                                                     \
        for (int s = 0; s < 4; ++s) {                                         \
            floatx4 a2 = MFMA(A2h[s][0], H1h0, bias2v[s]);                    \
            a2 = MFMA(A2h[s][1], H1h1, a2);                                   \
            a2 = MFMA(A2h[s][2], H2h0, a2);                                   \
            a2 = MFMA(A2h[s][3], H2h1, a2);                                   \
            floatx4 a1 = MFMA(Axwh[s], Bxh, bias1v[s]);                       \
            a1 = MFMA(A1h[s][0], H1h0, a1);                                   \
            a1 = MFMA(A1h[s][1], H1h1, a1);                                   \
            floatx4 g;                                                        \
            _Pragma("unroll")                                                 \
            for (int r = 0; r < 4; ++r) g[r] = isl2 ? a2[r] : a1[r];          \
            float& cs = (s == 0) ? cst0 : (s == 1) ? cst1 : (s == 2) ? cst2 : cst3; \
            const float h = cell_update(g, cs);                               \
            (HP)[((s & 2) << 5) + ((s & 1) << 2)] = bf16_rne(h);              \
        }                                                                     \
        __syncthreads();                                                      \
    }

    for (int i = 0; i < 254; i += 2) {
        STEP_BODY(0, 1, hpE)                 // interval i   (even)
        if (((i + 2) & 63) == 0) {           // refill before interval i+1
            refill_x(i + 2);
            xptr = xhi + b8 * XP;            //   next read is dt = 0
            __syncthreads();
        }
        STEP_BODY(1, 0, hpO)                 // interval i+1 (odd)
    }
    STEP_BODY(0, 1, hpE)                     // interval 254
#undef STEP_BODY

    // ================= epilogue: L2(255) =================
    {
        short8 H1h0 = *(const short8*)(h1hi + 1 * HSZ + ro8);
        short8 H1h1 = *(const short8*)(h1hi + 1 * HSZ + 256 + ro8);
        short8 H2h0 = *(const short8*)(h2hi + 0 * HSZ + ro8);
        short8 H2h1 = *(const short8*)(h2hi + 0 * HSZ + 256 + ro8);
        #pragma unroll
        for (int s = 0; s < 4; ++s) {
            floatx4 a2 = MFMA(A2h[s][0], H1h0, bias2v[s]);
            a2 = MFMA(A2h[s][1], H1h1, a2);
            a2 = MFMA(A2h[s][2], H2h0, a2);
            a2 = MFMA(A2h[s][3], H2h1, a2);
            if (isl2) {
                float& cs = (s == 0) ? cst0 : (s == 1) ? cst1 : (s == 2) ? cst2 : cst3;
                const float h = cell_update(a2, cs);
                h2f[b8 * HF + 16 * w + 4 * s + q] = h;
            }
        }
    }
    __syncthreads();

    // ================= FC epilogue =================
    if (tid < MT * OO) {
        const int bb = tid / OO, o = tid - bb * OO;
        float acc = bfc[o];
        const float* wr = Wfc + o * HH;
        const float* hr = h2f + bb * HF;
        #pragma unroll
        for (int j = 0; j < HH; ++j) acc += wr[j] * hr[j];
        out[((size_t)blockIdx.x * MT + bb) * OO + o] = acc;
    }
}

extern "C" void kernel_launch(void* const* d_in, const int* in_sizes, int n_in,
                              void* d_out, int out_size, void* d_ws, size_t ws_size,
                              hipStream_t stream) {
    const float* x    = (const float*)d_in[0];
    const float* Wih0 = (const float*)d_in[1];
    const float* Whh0 = (const float*)d_in[2];
    const float* bih0 = (const float*)d_in[3];
    const float* bhh0 = (const float*)d_in[4];
    const float* Wih1 = (const float*)d_in[5];
    const float* Whh1 = (const float*)d_in[6];
    const float* bih1 = (const float*)d_in[7];
    const float* bhh1 = (const float*)d_in[8];
    const float* Wfc  = (const float*)d_in[9];
    const float* bfc  = (const float*)d_in[10];
    float* out = (float*)d_out;

    dim3 grid(4096 / MT), block(NTHR);
    lstm_mfma15<<<grid, block, 0, stream>>>(x, Wih0, Whh0, bih0, bhh0,
                                            Wih1, Whh1, bih1, bhh1,
                                            Wfc, bfc, out);
}